// Round 1
// baseline (97.769 us; speedup 1.0000x reference)
//
#include <hip/hip_runtime.h>

// ---------------------------------------------------------------------------
// CausalFullAttention (decay-gated causal linear attention), MI355X gfx950
// b=2, n=2048, DIM=512, HEADS=8, DIM_HEAD=64  -> fixed sizes hardcoded
// Pipeline:
//  1) rmsnorm (fp32 -> bf16 xn)
//  2) wtrans x3: w_qkv,w_a -> wT[2048][512] bf16 ; w_out -> woT[512][512] bf16
//  3) gemm<0>: qkva[4][b][h][n][d] fp32 = xn @ [w_qkv|w_a] + bias
//  4) scan1: per-chunk local cumsum of log(clip(sigmoid(a)))
//  5) scan2: chunk-prefix + gates -> q2,k2 (row-major bf16) + k2T,vT ([bh][d][n])
//  6) kstate: per-chunk S^T[d][d'] = sum_j v[j][d] k2[j][d']  (fp32)
//  7) sprefix: exclusive prefix over chunks -> Spre bf16
//  8) attnk: out = q2 @ Spre + tril(q2 k2^T) @ v   (per chunk, MFMA)
//  9) gemm<1>: d_out = aout @ w_out^T + b_out  (fp32)
// ---------------------------------------------------------------------------

using s8v   = __attribute__((ext_vector_type(8))) short;   // 8 x bf16 bits
using f32x4 = __attribute__((ext_vector_type(4))) float;

__device__ __forceinline__ unsigned short f2b(float f) {
  unsigned int u = __builtin_bit_cast(unsigned int, f);
  u += 0x7FFFu + ((u >> 16) & 1u);          // RNE
  return (unsigned short)(u >> 16);
}

__device__ __forceinline__ f32x4 mfma16(s8v a, s8v b, f32x4 c) {
  return __builtin_amdgcn_mfma_f32_16x16x32_bf16(a, b, c, 0, 0, 0);
}

// ---------------- 1) RMSNorm: x[4096][512] f32 -> xnb bf16 -------------------
__global__ __launch_bounds__(256) void rmsnorm_k(const float* __restrict__ x,
                                                 const float* __restrict__ gamma,
                                                 short* __restrict__ xnb) {
  int row  = blockIdx.x * 4 + (threadIdx.x >> 6);
  int lane = threadIdx.x & 63;
  const float4* xp = reinterpret_cast<const float4*>(x + (size_t)row * 512 + lane * 8);
  float4 v0 = xp[0], v1 = xp[1];
  float ss = v0.x*v0.x + v0.y*v0.y + v0.z*v0.z + v0.w*v0.w
           + v1.x*v1.x + v1.y*v1.y + v1.z*v1.z + v1.w*v1.w;
#pragma unroll
  for (int off = 32; off > 0; off >>= 1) ss += __shfl_xor(ss, off, 64);
  float s = 22.627416997969522f / fmaxf(sqrtf(ss), 1e-12f);  // sqrt(512)/||x||
  const float* g = gamma + lane * 8;
  float vals[8] = {v0.x, v0.y, v0.z, v0.w, v1.x, v1.y, v1.z, v1.w};
  s8v o;
#pragma unroll
  for (int j = 0; j < 8; ++j) o[j] = (short)f2b(vals[j] * s * g[j]);
  *reinterpret_cast<s8v*>(xnb + (size_t)row * 512 + lane * 8) = o;
}

// ---------------- 2) transpose f32 [K][N] -> bf16 [N][K] ---------------------
__global__ void wtrans_k(const float* __restrict__ src, short* __restrict__ dst,
                         int K, int N) {
  __shared__ float t[32][33];
  int n0 = blockIdx.x * 32, k0 = blockIdx.y * 32;
  int tx = threadIdx.x, ty = threadIdx.y;
#pragma unroll
  for (int i = 0; i < 4; ++i)
    t[ty + 8 * i][tx] = src[(size_t)(k0 + ty + 8 * i) * N + n0 + tx];
  __syncthreads();
#pragma unroll
  for (int i = 0; i < 4; ++i)
    dst[(size_t)(n0 + ty + 8 * i) * K + k0 + tx] = (short)f2b(t[tx][ty + 8 * i]);
}

// ---------------- 3/9) GEMM: C[M][N] = A[M][K] * B[N][K]^T (+bias) -----------
// A,B bf16 row-major with K contiguous. 128x128 tile, BK=64, 4 waves (2x2).
// EPI=0: scatter fp32 into qkva[w][b][h][n][d] with bias = [b_qkv|b_a]
// EPI=1: fp32 out[row*N+col] + bias0[col]
template <int EPI>
__global__ __launch_bounds__(256) void gemm_bt(const short* __restrict__ A,
                                               const short* __restrict__ Bm,
                                               float* __restrict__ C,
                                               const float* __restrict__ bias0,
                                               const float* __restrict__ bias1,
                                               int M, int N, int K) {
  __shared__ __align__(16) char LA[128 * 128];  // 128 rows x 128B (64 bf16)
  __shared__ __align__(16) char LB[128 * 128];
  const int tid = threadIdx.x, lane = tid & 63, wave = tid >> 6;
  const int wr = (wave >> 1) * 64, wc = (wave & 1) * 64;
  const int m0 = blockIdx.y * 128, n0 = blockIdx.x * 128;
  f32x4 acc[4][4] = {};
  for (int k0 = 0; k0 < K; k0 += 64) {
    s8v ra[4], rb[4];
#pragma unroll
    for (int r = 0; r < 4; ++r) {
      int o = r * 4096 + tid * 16;
      int row = o >> 7, colb = o & 127;
      ra[r] = *reinterpret_cast<const s8v*>(A  + (size_t)(m0 + row) * K + k0 + (colb >> 1));
      rb[r] = *reinterpret_cast<const s8v*>(Bm + (size_t)(n0 + row) * K + k0 + (colb >> 1));
    }
    __syncthreads();
#pragma unroll
    for (int r = 0; r < 4; ++r) {
      int o = r * 4096 + tid * 16;
      int row = o >> 7;
      int ad = o ^ ((row & 7) << 4);  // XOR swizzle, bits 4-6
      *reinterpret_cast<s8v*>(LA + ad) = ra[r];
      *reinterpret_cast<s8v*>(LB + ad) = rb[r];
    }
    __syncthreads();
#pragma unroll
    for (int kk = 0; kk < 2; ++kk) {
      s8v af[4], bf[4];
#pragma unroll
      for (int m = 0; m < 4; ++m) {
        int row = wr + m * 16 + (lane & 15);
        int ad = (row << 7) + kk * 64 + ((lane >> 4) << 4);
        ad ^= (row & 7) << 4;
        af[m] = *reinterpret_cast<const s8v*>(LA + ad);
      }
#pragma unroll
      for (int n = 0; n < 4; ++n) {
        int row = wc + n * 16 + (lane & 15);
        int ad = (row << 7) + kk * 64 + ((lane >> 4) << 4);
        ad ^= (row & 7) << 4;
        bf[n] = *reinterpret_cast<const s8v*>(LB + ad);
      }
#pragma unroll
      for (int m = 0; m < 4; ++m)
#pragma unroll
        for (int n = 0; n < 4; ++n)
          acc[m][n] = mfma16(af[m], bf[n], acc[m][n]);
    }
  }
#pragma unroll
  for (int m = 0; m < 4; ++m)
#pragma unroll
    for (int n = 0; n < 4; ++n)
#pragma unroll
      for (int r = 0; r < 4; ++r) {
        int row = m0 + wr + m * 16 + ((lane >> 4) << 2) + r;
        int col = n0 + wc + n * 16 + (lane & 15);
        float v = acc[m][n][r];
        if constexpr (EPI == 0) {
          v += (col < 1536) ? bias0[col] : bias1[col - 1536];
          int w = col >> 9, h = (col >> 6) & 7, d = col & 63;
          int b = row >> 11, nn = row & 2047;
          C[((((size_t)(w * 2 + b)) * 8 + h) * 2048 + nn) * 64 + d] = v;
        } else {
          C[(size_t)row * N + col] = v + bias0[col];
        }
      }
}

// ---------------- 4) scan1: local cumsum of log-gate per chunk ---------------
__global__ __launch_bounds__(64) void scan1_k(const float* __restrict__ qkva,
                                              float* __restrict__ lc,
                                              float* __restrict__ csum) {
  int chunk = blockIdx.x, bh = blockIdx.y, d = threadIdx.x;
  int b = bh >> 3, h = bh & 7;
  const float* ap = qkva + ((((size_t)3 * 2 + b) * 8 + h) * 2048 + chunk * 64) * 64 + d;
  float* lp = lc + ((size_t)bh * 2048 + chunk * 64) * 64 + d;
  float s = 0.f;
  for (int r = 0; r < 64; ++r) {
    float xv = ap[r * 64];
    float a = 1.f / (1.f + expf(-xv));            // sigmoid
    a = fminf(fmaxf(a, 1e-10f), 1.f);             // clip
    s += logf(a);
    lp[r * 64] = s;
  }
  csum[((size_t)bh * 32 + chunk) * 64 + d] = s;
}

// ---------------- 5) scan2: gates + q2,k2,k2T,vT -----------------------------
__global__ __launch_bounds__(64) void scan2_k(const float* __restrict__ qkva,
                                              const float* __restrict__ lc,
                                              const float* __restrict__ csum,
                                              short* __restrict__ q2,
                                              short* __restrict__ k2,
                                              short* __restrict__ k2T,
                                              short* __restrict__ vT) {
  int chunk = blockIdx.x, bh = blockIdx.y, d = threadIdx.x;
  int b = bh >> 3, h = bh & 7;
  __shared__ short kL[64][72], vL[64][72];
  float pre = 0.f;
  for (int c = 0; c < chunk; ++c) pre += csum[((size_t)bh * 32 + c) * 64 + d];
  const size_t WS = (size_t)2 * 8 * 2048 * 64;  // stride between q/k/v planes
  size_t base = (((size_t)b * 8 + h) * 2048 + chunk * 64) * 64 + d;
  size_t rowbase = ((size_t)bh * 2048 + chunk * 64) * 64 + d;
  for (int r = 0; r < 64; ++r) {
    float s = pre + lc[rowbase + r * 64];
    float g = expf(s);                       // a_cum (fp32, underflow matches ref)
    float gi = 1.f / fmaxf(g, 1e-8f);        // a_cum_inv
    float qv = qkva[base + r * 64];
    float kv = qkva[base + WS + r * 64];
    float vv = qkva[base + 2 * WS + r * 64];
    q2[rowbase + r * 64] = (short)f2b(qv * 0.125f * g);   // SCALE = 64^-0.5
    unsigned short kb = f2b(kv * gi);
    k2[rowbase + r * 64] = (short)kb;
    kL[r][d] = (short)kb;
    vL[r][d] = (short)f2b(vv);
  }
  __syncthreads();
  short* k2Trow = k2T + ((size_t)bh * 64 + d) * 2048 + chunk * 64;
  short* vTrow  = vT  + ((size_t)bh * 64 + d) * 2048 + chunk * 64;
#pragma unroll
  for (int g8 = 0; g8 < 8; ++g8) {
    s8v pk, pv;
#pragma unroll
    for (int j = 0; j < 8; ++j) { pk[j] = kL[g8 * 8 + j][d]; pv[j] = vL[g8 * 8 + j][d]; }
    *reinterpret_cast<s8v*>(k2Trow + g8 * 8) = pk;
    *reinterpret_cast<s8v*>(vTrow  + g8 * 8) = pv;
  }
}

// ---------------- 6) kstate: S^T[d][d'] = sum_j v[j][d]*k2[j][d'] ------------
__global__ __launch_bounds__(64) void kstate_k(const short* __restrict__ k2T,
                                               const short* __restrict__ vT,
                                               float* __restrict__ Sbuf) {
  int chunk = blockIdx.x, bh = blockIdx.y, lane = threadIdx.x;
  __shared__ __align__(16) char LV[8192], LK[8192];
#pragma unroll
  for (int rr = 0; rr < 8; ++rr) {
    int o = rr * 1024 + lane * 16;
    int row = o >> 7, colb = o & 127;
    s8v av = *reinterpret_cast<const s8v*>(vT  + ((size_t)bh * 64 + row) * 2048 + chunk * 64 + (colb >> 1));
    s8v ak = *reinterpret_cast<const s8v*>(k2T + ((size_t)bh * 64 + row) * 2048 + chunk * 64 + (colb >> 1));
    int ad = o ^ ((row & 7) << 4);
    *reinterpret_cast<s8v*>(LV + ad) = av;
    *reinterpret_cast<s8v*>(LK + ad) = ak;
  }
  __syncthreads();
  f32x4 acc[4][4] = {};
#pragma unroll
  for (int kk = 0; kk < 2; ++kk) {
    s8v av[4], bk[4];
#pragma unroll
    for (int m = 0; m < 4; ++m) {
      int row = m * 16 + (lane & 15);
      int ad = (row << 7) + kk * 64 + ((lane >> 4) << 4);
      ad ^= (row & 7) << 4;
      av[m] = *reinterpret_cast<const s8v*>(LV + ad);
      bk[m] = *reinterpret_cast<const s8v*>(LK + ad);
    }
#pragma unroll
    for (int m = 0; m < 4; ++m)
#pragma unroll
      for (int n = 0; n < 4; ++n)
        acc[m][n] = mfma16(av[m], bk[n], acc[m][n]);
  }
  float* Sp = Sbuf + ((size_t)bh * 32 + chunk) * 4096;
#pragma unroll
  for (int m = 0; m < 4; ++m)
#pragma unroll
    for (int n = 0; n < 4; ++n)
#pragma unroll
      for (int r = 0; r < 4; ++r)
        Sp[(m * 16 + ((lane >> 4) << 2) + r) * 64 + n * 16 + (lane & 15)] = acc[m][n][r];
}

// ---------------- 7) sprefix: exclusive prefix of states, -> bf16 ------------
__global__ __launch_bounds__(256) void sprefix_k(const float* __restrict__ Sbuf,
                                                 short* __restrict__ Spre) {
  int bh = blockIdx.x >> 4;
  int e = ((blockIdx.x & 15) << 8) + threadIdx.x;
  size_t base = (size_t)bh * 32 * 4096 + e;
  float acc = 0.f;
  for (int c = 0; c < 32; ++c) {
    Spre[base + (size_t)c * 4096] = (short)f2b(acc);
    acc += Sbuf[base + (size_t)c * 4096];
  }
}

// ---------------- 8) attnk: out = q2@Spre + tril(q2 k2^T)@v ------------------
__global__ __launch_bounds__(256) void attnk_k(const short* __restrict__ q2,
                                               const short* __restrict__ k2,
                                               const short* __restrict__ vT,
                                               const short* __restrict__ Spre,
                                               short* __restrict__ aout) {
  int chunk = blockIdx.x, bh = blockIdx.y;
  int tid = threadIdx.x, lane = tid & 63, wave = tid >> 6;
  __shared__ __align__(16) char LQ[8192], LK[8192], LV[8192], LS[8192], LP[8192];
#pragma unroll
  for (int rr = 0; rr < 2; ++rr) {
    int o = rr * 4096 + tid * 16;
    int row = o >> 7, colb = o & 127;
    int ad = o ^ ((row & 7) << 4);
    *reinterpret_cast<s8v*>(LQ + ad) =
        *reinterpret_cast<const s8v*>(q2 + ((size_t)bh * 2048 + chunk * 64 + row) * 64 + (colb >> 1));
    *reinterpret_cast<s8v*>(LK + ad) =
        *reinterpret_cast<const s8v*>(k2 + ((size_t)bh * 2048 + chunk * 64 + row) * 64 + (colb >> 1));
    *reinterpret_cast<s8v*>(LV + ad) =
        *reinterpret_cast<const s8v*>(vT + ((size_t)bh * 64 + row) * 2048 + chunk * 64 + (colb >> 1));
    *reinterpret_cast<s8v*>(LS + ad) =
        *reinterpret_cast<const s8v*>(Spre + (((size_t)bh * 32 + chunk) * 64 + row) * 64 + (colb >> 1));
  }
  __syncthreads();
  f32x4 accS[4] = {}, accO[4] = {};
#pragma unroll
  for (int kk = 0; kk < 2; ++kk) {
    int arow = wave * 16 + (lane & 15);
    int aad = (arow << 7) + kk * 64 + ((lane >> 4) << 4);
    aad ^= (arow & 7) << 4;
    s8v aq = *reinterpret_cast<const s8v*>(LQ + aad);
#pragma unroll
    for (int n = 0; n < 4; ++n) {
      int brow = n * 16 + (lane & 15);
      int bad = (brow << 7) + kk * 64 + ((lane >> 4) << 4);
      bad ^= (brow & 7) << 4;
      accS[n] = mfma16(aq, *reinterpret_cast<const s8v*>(LK + bad), accS[n]);
      accO[n] = mfma16(aq, *reinterpret_cast<const s8v*>(LS + bad), accO[n]);
    }
  }
  // causal mask within chunk, write P (bf16, swizzled)
#pragma unroll
  for (int n = 0; n < 4; ++n)
#pragma unroll
    for (int r = 0; r < 4; ++r) {
      int i = wave * 16 + ((lane >> 4) << 2) + r;
      int j = n * 16 + (lane & 15);
      float v = (j <= i) ? accS[n][r] : 0.f;
      int ad = (i << 7) + (j << 1);
      ad ^= (i & 7) << 4;
      *reinterpret_cast<short*>(LP + ad) = (short)f2b(v);
    }
  __syncthreads();
#pragma unroll
  for (int kk = 0; kk < 2; ++kk) {
    int arow = wave * 16 + (lane & 15);
    int aad = (arow << 7) + kk * 64 + ((lane >> 4) << 4);
    aad ^= (arow & 7) << 4;
    s8v ap = *reinterpret_cast<const s8v*>(LP + aad);
#pragma unroll
    for (int n = 0; n < 4; ++n) {
      int brow = n * 16 + (lane & 15);
      int bad = (brow << 7) + kk * 64 + ((lane >> 4) << 4);
      bad ^= (brow & 7) << 4;
      accO[n] = mfma16(ap, *reinterpret_cast<const s8v*>(LV + bad), accO[n]);
    }
  }
  int b = bh >> 3, h = bh & 7;
#pragma unroll
  for (int n = 0; n < 4; ++n)
#pragma unroll
    for (int r = 0; r < 4; ++r) {
      int i = wave * 16 + ((lane >> 4) << 2) + r;
      int col = h * 64 + n * 16 + (lane & 15);
      size_t row = (size_t)b * 2048 + chunk * 64 + i;
      aout[row * 512 + col] = (short)f2b(accO[n][r]);
    }
}

// ---------------------------------------------------------------------------
extern "C" void kernel_launch(void* const* d_in, const int* in_sizes, int n_in,
                              void* d_out, int out_size, void* d_ws, size_t ws_size,
                              hipStream_t stream) {
  const float* x     = (const float*)d_in[0];
  const float* gamma = (const float*)d_in[1];
  const float* w_qkv = (const float*)d_in[2];
  const float* b_qkv = (const float*)d_in[3];
  const float* w_a   = (const float*)d_in[4];
  const float* b_a   = (const float*)d_in[5];
  const float* w_out = (const float*)d_in[6];
  const float* b_out = (const float*)d_in[7];
  float* out = (float*)d_out;
  char* ws = (char*)d_ws;

  const size_t MB = 1u << 20;
  short* xnb  = (short*)(ws);                 // 4 MiB   [4096][512] bf16
  short* wT   = (short*)(ws + 4  * MB);       // 2 MiB   [2048][512] bf16
  short* woT  = (short*)(ws + 6  * MB);       // 0.5 MiB [512][512]  bf16
  float* qkva = (float*)(ws + 7  * MB);       // 32 MiB  [4][2][8][2048][64] f32
  float* lc   = (float*)(ws + 39 * MB);       // 8 MiB   [16][2048][64] f32
  float* csum = (float*)(ws + 47 * MB);       // 128 KiB [16][32][64] f32
  short* q2   = (short*)(ws + 48 * MB);       // 4 MiB   [16][2048][64] bf16
  short* k2   = (short*)(ws + 52 * MB);       // 4 MiB
  short* k2T  = (short*)(ws + 56 * MB);       // 4 MiB   [16][64][2048]
  short* vT   = (short*)(ws + 60 * MB);       // 4 MiB   [16][64][2048]
  // aliases (lifetimes disjoint, stream-ordered):
  float* Sbuf = (float*)(ws + 7  * MB);       // 8 MiB, reuses qkva (dead after scan2)
  short* Spre = (short*)(ws + 15 * MB);       // 4 MiB, reuses qkva tail
  short* aout = (short*)(ws + 39 * MB);       // 4 MiB, reuses lc (dead after scan2)

  rmsnorm_k<<<1024, 256, 0, stream>>>(x, gamma, xnb);

  dim3 tb(32, 8);
  wtrans_k<<<dim3(48, 16), tb, 0, stream>>>(w_qkv, wT, 512, 1536);
  wtrans_k<<<dim3(16, 16), tb, 0, stream>>>(w_a,  wT + (size_t)1536 * 512, 512, 512);
  wtrans_k<<<dim3(16, 16), tb, 0, stream>>>(w_out, woT, 512, 512);

  gemm_bt<0><<<dim3(16, 32), 256, 0, stream>>>(xnb, wT, qkva, b_qkv, b_a, 4096, 2048, 512);

  scan1_k<<<dim3(32, 16), 64, 0, stream>>>(qkva, lc, csum);
  scan2_k<<<dim3(32, 16), 64, 0, stream>>>(qkva, lc, csum, q2, k2, k2T, vT);

  kstate_k <<<dim3(32, 16), 64,  0, stream>>>(k2T, vT, Sbuf);
  sprefix_k<<<256, 256, 0, stream>>>(Sbuf, Spre);
  attnk_k  <<<dim3(32, 16), 256, 0, stream>>>(q2, k2, vT, Spre, aout);

  gemm_bt<1><<<dim3(4, 32), 256, 0, stream>>>(aout, woT, out, b_out, b_out, 4096, 512, 512);
}

// Round 2
// 75.511 us; speedup vs baseline: 1.2948x; 1.2948x over previous
//
#include <hip/hip_runtime.h>

// ---------------------------------------------------------------------------
// CausalFullAttention (decay-gated causal linear attention), MI355X gfx950
// b=2, n=2048, DIM=512, HEADS=8, DIM_HEAD=64
// R2: global_load_lds GEMM staging (pre-swizzled source), 64x64 output GEMM,
//     scan2 4-wave + folded kstate, fused wtrans. 8 dispatches.
// ---------------------------------------------------------------------------

using s8v   = __attribute__((ext_vector_type(8))) short;   // 8 x bf16 bits
using f32x4 = __attribute__((ext_vector_type(4))) float;

__device__ __forceinline__ unsigned short f2b(float f) {
  unsigned int u = __builtin_bit_cast(unsigned int, f);
  u += 0x7FFFu + ((u >> 16) & 1u);          // RNE
  return (unsigned short)(u >> 16);
}

__device__ __forceinline__ f32x4 mfma16(s8v a, s8v b, f32x4 c) {
  return __builtin_amdgcn_mfma_f32_16x16x32_bf16(a, b, c, 0, 0, 0);
}

// async global->LDS, 16B per lane; LDS dest must be wave-uniform base + lane*16
__device__ __forceinline__ void gload16(const void* g, void* l) {
  __builtin_amdgcn_global_load_lds(
      (const __attribute__((address_space(1))) void*)g,
      (__attribute__((address_space(3))) void*)l, 16, 0, 0);
}

// ---------------- 1) RMSNorm: x[4096][512] f32 -> xnb bf16 -------------------
__global__ __launch_bounds__(256) void rmsnorm_k(const float* __restrict__ x,
                                                 const float* __restrict__ gamma,
                                                 short* __restrict__ xnb) {
  int row  = blockIdx.x * 4 + (threadIdx.x >> 6);
  int lane = threadIdx.x & 63;
  const float4* xp = reinterpret_cast<const float4*>(x + (size_t)row * 512 + lane * 8);
  float4 v0 = xp[0], v1 = xp[1];
  float ss = v0.x*v0.x + v0.y*v0.y + v0.z*v0.z + v0.w*v0.w
           + v1.x*v1.x + v1.y*v1.y + v1.z*v1.z + v1.w*v1.w;
#pragma unroll
  for (int off = 32; off > 0; off >>= 1) ss += __shfl_xor(ss, off, 64);
  float s = 22.627416997969522f / fmaxf(sqrtf(ss), 1e-12f);  // sqrt(512)/||x||
  const float* g = gamma + lane * 8;
  float vals[8] = {v0.x, v0.y, v0.z, v0.w, v1.x, v1.y, v1.z, v1.w};
  s8v o;
#pragma unroll
  for (int j = 0; j < 8; ++j) o[j] = (short)f2b(vals[j] * s * g[j]);
  *reinterpret_cast<s8v*>(xnb + (size_t)row * 512 + lane * 8) = o;
}

// ---------------- 2) fused transposes f32 [512][N] -> bf16 [N][512] ----------
__global__ void wtrans_k(const float* __restrict__ w_qkv,
                         const float* __restrict__ w_a,
                         const float* __restrict__ w_out,
                         short* __restrict__ wT, short* __restrict__ woT) {
  __shared__ float t[32][33];
  int bx = blockIdx.x, k0 = blockIdx.y * 32;
  const float* src; short* dst; int N, n0;
  if (bx < 48)      { src = w_qkv; dst = wT;                        N = 1536; n0 = bx * 32; }
  else if (bx < 64) { src = w_a;   dst = wT + (size_t)1536 * 512;   N = 512;  n0 = (bx - 48) * 32; }
  else              { src = w_out; dst = woT;                       N = 512;  n0 = (bx - 64) * 32; }
  int tx = threadIdx.x, ty = threadIdx.y;
#pragma unroll
  for (int i = 0; i < 4; ++i)
    t[ty + 8 * i][tx] = src[(size_t)(k0 + ty + 8 * i) * N + n0 + tx];
  __syncthreads();
#pragma unroll
  for (int i = 0; i < 4; ++i)
    dst[(size_t)(n0 + ty + 8 * i) * 512 + k0 + tx] = (short)f2b(t[tx][ty + 8 * i]);
}

// ---------------- 3/9) GEMM: C[M][N] = A[M][K] * B[N][K]^T (+bias) -----------
// global_load_lds staging: LDS is linear; XOR swizzle applied to the per-lane
// GLOBAL source column, read-side XOR unchanged (both-sides rule).
// EPI=0: scatter fp32 into qkva[w][b][h][n][d], bias=[b_qkv|b_a]
// EPI=1: fp32 C[row*N+col] + bias0[col]
template <int BM, int BN, int EPI>
__global__ __launch_bounds__(256) void gemm_bt(const short* __restrict__ A,
                                               const short* __restrict__ Bm,
                                               float* __restrict__ C,
                                               const float* __restrict__ bias0,
                                               const float* __restrict__ bias1,
                                               int M, int N, int K) {
  __shared__ __align__(16) char LA[BM * 128];
  __shared__ __align__(16) char LB[BN * 128];
  constexpr int WM = BM / 2, WN = BN / 2, FM = WM / 16, FN = WN / 16;
  const int tid = threadIdx.x, lane = tid & 63, wave = tid >> 6;
  const int wr = (wave >> 1) * WM, wc = (wave & 1) * WN;
  const int m0 = blockIdx.y * BM, n0 = blockIdx.x * BN;
  f32x4 acc[FM][FN] = {};
  for (int k0 = 0; k0 < K; k0 += 64) {
#pragma unroll
    for (int r = 0; r < BM / 32; ++r) {
      int o = r * 4096 + tid * 16;
      int row = o >> 7;
      int ce = (((o & 127) ^ ((row & 7) << 4)) >> 1);   // pre-swizzled src col
      gload16(A + (size_t)(m0 + row) * K + k0 + ce, LA + o);
    }
#pragma unroll
    for (int r = 0; r < BN / 32; ++r) {
      int o = r * 4096 + tid * 16;
      int row = o >> 7;
      int ce = (((o & 127) ^ ((row & 7) << 4)) >> 1);
      gload16(Bm + (size_t)(n0 + row) * K + k0 + ce, LB + o);
    }
    __syncthreads();
#pragma unroll
    for (int kk = 0; kk < 2; ++kk) {
      s8v af[FM], bf[FN];
#pragma unroll
      for (int m = 0; m < FM; ++m) {
        int row = wr + m * 16 + (lane & 15);
        int ad = ((row << 7) + kk * 64 + ((lane >> 4) << 4)) ^ ((row & 7) << 4);
        af[m] = *reinterpret_cast<const s8v*>(LA + ad);
      }
#pragma unroll
      for (int n = 0; n < FN; ++n) {
        int row = wc + n * 16 + (lane & 15);
        int ad = ((row << 7) + kk * 64 + ((lane >> 4) << 4)) ^ ((row & 7) << 4);
        bf[n] = *reinterpret_cast<const s8v*>(LB + ad);
      }
#pragma unroll
      for (int m = 0; m < FM; ++m)
#pragma unroll
        for (int n = 0; n < FN; ++n)
          acc[m][n] = mfma16(af[m], bf[n], acc[m][n]);
    }
    __syncthreads();
  }
#pragma unroll
  for (int m = 0; m < FM; ++m)
#pragma unroll
    for (int n = 0; n < FN; ++n)
#pragma unroll
      for (int r = 0; r < 4; ++r) {
        int row = m0 + wr + m * 16 + ((lane >> 4) << 2) + r;
        int col = n0 + wc + n * 16 + (lane & 15);
        float v = acc[m][n][r];
        if constexpr (EPI == 0) {
          v += (col < 1536) ? bias0[col] : bias1[col - 1536];
          int w = col >> 9, h = (col >> 6) & 7, d = col & 63;
          int b = row >> 11, nn = row & 2047;
          C[((((size_t)(w * 2 + b)) * 8 + h) * 2048 + nn) * 64 + d] = v;
        } else {
          C[(size_t)row * N + col] = v + bias0[col];
        }
      }
}

// ---------------- 4) scan1: local cumsum of log-gate per chunk ---------------
__global__ __launch_bounds__(64) void scan1_k(const float* __restrict__ qkva,
                                              float* __restrict__ lc,
                                              float* __restrict__ csum) {
  int chunk = blockIdx.x, bh = blockIdx.y, d = threadIdx.x;
  int b = bh >> 3, h = bh & 7;
  const float* ap = qkva + ((((size_t)3 * 2 + b) * 8 + h) * 2048 + chunk * 64) * 64 + d;
  float* lp = lc + ((size_t)bh * 2048 + chunk * 64) * 64 + d;
  float s = 0.f;
  for (int r = 0; r < 64; ++r) {
    float xv = ap[r * 64];
    float a = 1.f / (1.f + expf(-xv));            // sigmoid
    a = fminf(fmaxf(a, 1e-10f), 1.f);             // clip
    s += logf(a);
    lp[r * 64] = s;
  }
  csum[((size_t)bh * 32 + chunk) * 64 + d] = s;
}

// ---------------- 5) scan2: gates -> q2,k2,vT + folded kstate (S per chunk) --
__global__ __launch_bounds__(256) void scan2_k(const float* __restrict__ qkva,
                                               const float* __restrict__ lc,
                                               const float* __restrict__ csum,
                                               short* __restrict__ q2,
                                               short* __restrict__ k2,
                                               short* __restrict__ vT,
                                               float* __restrict__ Sbuf) {
  int chunk = blockIdx.x, bh = blockIdx.y;
  int tid = threadIdx.x, lane = tid & 63, wave = tid >> 6;
  int b = bh >> 3, h = bh & 7, d = lane;
  __shared__ short kL[64][72], vL[64][72];
  __shared__ __align__(16) char kT[8192], vTl[8192];
  float pre = 0.f;
  for (int c = 0; c < chunk; ++c) pre += csum[((size_t)bh * 32 + c) * 64 + d];
  const size_t WS = (size_t)2 * 8 * 2048 * 64;
  size_t base = (((size_t)b * 8 + h) * 2048 + chunk * 64) * 64 + d;
  size_t rowbase = ((size_t)bh * 2048 + chunk * 64) * 64 + d;
#pragma unroll 4
  for (int rr = 0; rr < 16; ++rr) {
    int r = wave * 16 + rr;
    float s = pre + lc[rowbase + r * 64];
    float g = expf(s);                       // a_cum
    float gi = 1.f / fmaxf(g, 1e-8f);        // a_cum_inv
    float qv = qkva[base + r * 64];
    float kv = qkva[base + WS + r * 64];
    float vv = qkva[base + 2 * WS + r * 64];
    q2[rowbase + r * 64] = (short)f2b(qv * 0.125f * g);   // SCALE = 64^-0.5
    unsigned short kb = f2b(kv * gi);
    k2[rowbase + r * 64] = (short)kb;
    kL[r][d] = (short)kb;
    vL[r][d] = (short)f2b(vv);
  }
  __syncthreads();
  // transpose to global vT and to LDS [d][j] tiles (XOR-swizzled) for kstate
  short* vTrow = vT + ((size_t)bh * 64 + d) * 2048 + chunk * 64;
#pragma unroll
  for (int gg = 0; gg < 2; ++gg) {
    int g8 = wave + gg * 4;
    s8v pk, pv;
#pragma unroll
    for (int j = 0; j < 8; ++j) { pk[j] = kL[g8 * 8 + j][d]; pv[j] = vL[g8 * 8 + j][d]; }
    *reinterpret_cast<s8v*>(vTrow + g8 * 8) = pv;
    int ad = ((d << 7) + g8 * 16) ^ ((d & 7) << 4);
    *reinterpret_cast<s8v*>(kT  + ad) = pk;
    *reinterpret_cast<s8v*>(vTl + ad) = pv;
  }
  __syncthreads();
  // kstate: wave w computes S rows [w*16, w*16+16): S[d][d'] = sum_j V[j][d] k2[j][d']
  f32x4 acc[4] = {};
#pragma unroll
  for (int kk = 0; kk < 2; ++kk) {
    int arow = wave * 16 + (lane & 15);
    int aad = ((arow << 7) + kk * 64 + ((lane >> 4) << 4)) ^ ((arow & 7) << 4);
    s8v av = *reinterpret_cast<const s8v*>(vTl + aad);
#pragma unroll
    for (int n = 0; n < 4; ++n) {
      int brow = n * 16 + (lane & 15);
      int bad = ((brow << 7) + kk * 64 + ((lane >> 4) << 4)) ^ ((brow & 7) << 4);
      acc[n] = mfma16(av, *reinterpret_cast<const s8v*>(kT + bad), acc[n]);
    }
  }
  float* Sp = Sbuf + ((size_t)bh * 32 + chunk) * 4096;
#pragma unroll
  for (int n = 0; n < 4; ++n)
#pragma unroll
    for (int r = 0; r < 4; ++r)
      Sp[(wave * 16 + ((lane >> 4) << 2) + r) * 64 + n * 16 + (lane & 15)] = acc[n][r];
}

// ---------------- 7) sprefix: exclusive prefix of states, -> bf16 ------------
__global__ __launch_bounds__(256) void sprefix_k(const float* __restrict__ Sbuf,
                                                 short* __restrict__ Spre) {
  int bh = blockIdx.x >> 4;
  int e = ((blockIdx.x & 15) << 8) + threadIdx.x;
  size_t base = (size_t)bh * 32 * 4096 + e;
  float acc = 0.f;
  for (int c = 0; c < 32; ++c) {
    Spre[base + (size_t)c * 4096] = (short)f2b(acc);
    acc += Sbuf[base + (size_t)c * 4096];
  }
}

// ---------------- 8) attnk: out = q2@Spre + tril(q2 k2^T)@v ------------------
__global__ __launch_bounds__(256) void attnk_k(const short* __restrict__ q2,
                                               const short* __restrict__ k2,
                                               const short* __restrict__ vT,
                                               const short* __restrict__ Spre,
                                               short* __restrict__ aout) {
  int chunk = blockIdx.x, bh = blockIdx.y;
  int tid = threadIdx.x, lane = tid & 63, wave = tid >> 6;
  __shared__ __align__(16) char LQ[8192], LK[8192], LV[8192], LS[8192], LP[8192];
#pragma unroll
  for (int rr = 0; rr < 2; ++rr) {
    int o = rr * 4096 + tid * 16;
    int row = o >> 7;
    int ce = (((o & 127) ^ ((row & 7) << 4)) >> 1);
    gload16(q2   + ((size_t)bh * 2048 + chunk * 64 + row) * 64 + ce, LQ + o);
    gload16(k2   + ((size_t)bh * 2048 + chunk * 64 + row) * 64 + ce, LK + o);
    gload16(vT   + ((size_t)bh * 64 + row) * 2048 + chunk * 64 + ce, LV + o);
    gload16(Spre + (((size_t)bh * 32 + chunk) * 64 + row) * 64 + ce, LS + o);
  }
  __syncthreads();
  f32x4 accS[4] = {}, accO[4] = {};
#pragma unroll
  for (int kk = 0; kk < 2; ++kk) {
    int arow = wave * 16 + (lane & 15);
    int aad = ((arow << 7) + kk * 64 + ((lane >> 4) << 4)) ^ ((arow & 7) << 4);
    s8v aq = *reinterpret_cast<const s8v*>(LQ + aad);
#pragma unroll
    for (int n = 0; n < 4; ++n) {
      int brow = n * 16 + (lane & 15);
      int bad = ((brow << 7) + kk * 64 + ((lane >> 4) << 4)) ^ ((brow & 7) << 4);
      accS[n] = mfma16(aq, *reinterpret_cast<const s8v*>(LK + bad), accS[n]);
      accO[n] = mfma16(aq, *reinterpret_cast<const s8v*>(LS + bad), accO[n]);
    }
  }
  // causal mask within chunk, write P (bf16, swizzled)
#pragma unroll
  for (int n = 0; n < 4; ++n)
#pragma unroll
    for (int r = 0; r < 4; ++r) {
      int i = wave * 16 + ((lane >> 4) << 2) + r;
      int j = n * 16 + (lane & 15);
      float v = (j <= i) ? accS[n][r] : 0.f;
      int ad = ((i << 7) + (j << 1)) ^ ((i & 7) << 4);
      *reinterpret_cast<short*>(LP + ad) = (short)f2b(v);
    }
  __syncthreads();
#pragma unroll
  for (int kk = 0; kk < 2; ++kk) {
    int arow = wave * 16 + (lane & 15);
    int aad = ((arow << 7) + kk * 64 + ((lane >> 4) << 4)) ^ ((arow & 7) << 4);
    s8v ap = *reinterpret_cast<const s8v*>(LP + aad);
#pragma unroll
    for (int n = 0; n < 4; ++n) {
      int brow = n * 16 + (lane & 15);
      int bad = ((brow << 7) + kk * 64 + ((lane >> 4) << 4)) ^ ((brow & 7) << 4);
      accO[n] = mfma16(ap, *reinterpret_cast<const s8v*>(LV + bad), accO[n]);
    }
  }
  int b = bh >> 3, h = bh & 7;
#pragma unroll
  for (int n = 0; n < 4; ++n)
#pragma unroll
    for (int r = 0; r < 4; ++r) {
      int i = wave * 16 + ((lane >> 4) << 2) + r;
      int col = h * 64 + n * 16 + (lane & 15);
      size_t row = (size_t)b * 2048 + chunk * 64 + i;
      aout[row * 512 + col] = (short)f2b(accO[n][r]);
    }
}

// ---------------------------------------------------------------------------
extern "C" void kernel_launch(void* const* d_in, const int* in_sizes, int n_in,
                              void* d_out, int out_size, void* d_ws, size_t ws_size,
                              hipStream_t stream) {
  const float* x     = (const float*)d_in[0];
  const float* gamma = (const float*)d_in[1];
  const float* w_qkv = (const float*)d_in[2];
  const float* b_qkv = (const float*)d_in[3];
  const float* w_a   = (const float*)d_in[4];
  const float* b_a   = (const float*)d_in[5];
  const float* w_out = (const float*)d_in[6];
  const float* b_out = (const float*)d_in[7];
  float* out = (float*)d_out;
  char* ws = (char*)d_ws;

  const size_t MB = 1u << 20;
  short* xnb  = (short*)(ws);                 // 4 MiB   [4096][512] bf16
  short* wT   = (short*)(ws + 4  * MB);       // 2 MiB   [2048][512] bf16
  short* woT  = (short*)(ws + 6  * MB);       // 0.5 MiB [512][512]  bf16
  float* qkva = (float*)(ws + 7  * MB);       // 32 MiB  [4][2][8][2048][64] f32
  float* lc   = (float*)(ws + 39 * MB);       // 8 MiB   [16][2048][64] f32
  float* csum = (float*)(ws + 47 * MB);       // 128 KiB [16][32][64] f32
  short* q2   = (short*)(ws + 48 * MB);       // 4 MiB   [16][2048][64] bf16
  short* k2   = (short*)(ws + 52 * MB);       // 4 MiB
  short* vT   = (short*)(ws + 56 * MB);       // 4 MiB   [16][64][2048]
  float* Sbuf = (float*)(ws + 60 * MB);       // 8 MiB   [16][32][64][64] f32
  // aliases (lifetimes disjoint, stream-ordered):
  short* Spre = (short*)(ws + 7  * MB);       // 4 MiB, reuses qkva (dead after scan2)
  short* aout = (short*)(ws + 39 * MB);       // 4 MiB, reuses lc (dead after scan2)

  rmsnorm_k<<<1024, 256, 0, stream>>>(x, gamma, xnb);
  wtrans_k<<<dim3(80, 16), dim3(32, 8), 0, stream>>>(w_qkv, w_a, w_out, wT, woT);

  gemm_bt<128, 128, 0><<<dim3(16, 32), 256, 0, stream>>>(xnb, wT, qkva, b_qkv, b_a, 4096, 2048, 512);

  scan1_k<<<dim3(32, 16), 64, 0, stream>>>(qkva, lc, csum);
  scan2_k<<<dim3(32, 16), 256, 0, stream>>>(qkva, lc, csum, q2, k2, vT, Sbuf);

  sprefix_k<<<256, 256, 0, stream>>>(Sbuf, Spre);
  attnk_k<<<dim3(32, 16), 256, 0, stream>>>(q2, k2, vT, Spre, aout);

  gemm_bt<64, 64, 1><<<dim3(8, 64), 256, 0, stream>>>(aout, woT, out, b_out, b_out, 4096, 512, 512);
}

// Round 3
// 68.679 us; speedup vs baseline: 1.4236x; 1.0995x over previous
//
#include <hip/hip_runtime.h>

// ---------------------------------------------------------------------------
// CausalFullAttention (decay-gated causal linear attention), MI355X gfx950
// b=2, n=2048, DIM=512, HEADS=8, DIM_HEAD=64
// R3: scan1 fused into gemm<0> epilogue (in-LDS chunk cumsum); qkv + Sbuf in
//     bf16; rmsnorm+wtrans fused. 6 dispatches.
// ---------------------------------------------------------------------------

using s8v   = __attribute__((ext_vector_type(8))) short;   // 8 x bf16 bits
using f32x4 = __attribute__((ext_vector_type(4))) float;

__device__ __forceinline__ unsigned short f2b(float f) {
  unsigned int u = __builtin_bit_cast(unsigned int, f);
  u += 0x7FFFu + ((u >> 16) & 1u);          // RNE
  return (unsigned short)(u >> 16);
}
__device__ __forceinline__ float b2f(unsigned short b) {
  unsigned int u = ((unsigned int)b) << 16;
  return __builtin_bit_cast(float, u);
}

__device__ __forceinline__ f32x4 mfma16(s8v a, s8v b, f32x4 c) {
  return __builtin_amdgcn_mfma_f32_16x16x32_bf16(a, b, c, 0, 0, 0);
}

// async global->LDS, 16B per lane; LDS dest must be wave-uniform base + lane*16
__device__ __forceinline__ void gload16(const void* g, void* l) {
  __builtin_amdgcn_global_load_lds(
      (const __attribute__((address_space(1))) void*)g,
      (__attribute__((address_space(3))) void*)l, 16, 0, 0);
}

// ---------------- 1) prep: rmsnorm (blocks 0-1023) + wtrans (1024-2303) -----
__global__ __launch_bounds__(256) void prep_k(const float* __restrict__ x,
                                              const float* __restrict__ gamma,
                                              short* __restrict__ xnb,
                                              const float* __restrict__ w_qkv,
                                              const float* __restrict__ w_a,
                                              const float* __restrict__ w_out,
                                              short* __restrict__ wT,
                                              short* __restrict__ woT) {
  __shared__ float t[32][33];
  int bid = blockIdx.x;
  if (bid < 1024) {
    int row  = bid * 4 + (threadIdx.x >> 6);
    int lane = threadIdx.x & 63;
    const float4* xp = reinterpret_cast<const float4*>(x + (size_t)row * 512 + lane * 8);
    float4 v0 = xp[0], v1 = xp[1];
    float ss = v0.x*v0.x + v0.y*v0.y + v0.z*v0.z + v0.w*v0.w
             + v1.x*v1.x + v1.y*v1.y + v1.z*v1.z + v1.w*v1.w;
#pragma unroll
    for (int off = 32; off > 0; off >>= 1) ss += __shfl_xor(ss, off, 64);
    float s = 22.627416997969522f / fmaxf(sqrtf(ss), 1e-12f);
    const float* g = gamma + lane * 8;
    float vals[8] = {v0.x, v0.y, v0.z, v0.w, v1.x, v1.y, v1.z, v1.w};
    s8v o;
#pragma unroll
    for (int j = 0; j < 8; ++j) o[j] = (short)f2b(vals[j] * s * g[j]);
    *reinterpret_cast<s8v*>(xnb + (size_t)row * 512 + lane * 8) = o;
  } else {
    int id = bid - 1024;
    int bx = id % 80, k0 = (id / 80) * 32;
    const float* src; short* dst; int N, n0;
    if (bx < 48)      { src = w_qkv; dst = wT;                      N = 1536; n0 = bx * 32; }
    else if (bx < 64) { src = w_a;   dst = wT + (size_t)1536 * 512; N = 512;  n0 = (bx - 48) * 32; }
    else              { src = w_out; dst = woT;                     N = 512;  n0 = (bx - 64) * 32; }
    int tx = threadIdx.x & 31, ty = threadIdx.x >> 5;
#pragma unroll
    for (int i = 0; i < 4; ++i)
      t[ty + 8 * i][tx] = src[(size_t)(k0 + ty + 8 * i) * N + n0 + tx];
    __syncthreads();
#pragma unroll
    for (int i = 0; i < 4; ++i)
      dst[(size_t)(n0 + ty + 8 * i) * 512 + k0 + tx] = (short)f2b(t[tx][ty + 8 * i]);
  }
}

// ---------------- 2/6) GEMM: C[M][N] = A[M][K] * B[N][K]^T (+bias) -----------
// EPI=0: cols<1536 -> qkvb bf16 [3][b][h][n][64]; cols>=1536 -> gate path:
//        la=log(clip(sigmoid)), in-LDS per-chunk cumsum -> lc fp32 + csum.
// EPI=1: fp32 C[row*N+col] + bias0[col]
template <int BM, int BN, int EPI>
__global__ __launch_bounds__(256) void gemm_bt(const short* __restrict__ A,
                                               const short* __restrict__ Bm,
                                               void* __restrict__ Cout,
                                               const float* __restrict__ bias0,
                                               const float* __restrict__ bias1,
                                               float* __restrict__ lc,
                                               float* __restrict__ csum,
                                               int M, int N, int K) {
  constexpr int ARENA_SZ = (EPI == 0) ? (128 * 133 * 4) : (BM * 128 + BN * 128);
  __shared__ __align__(16) char ARENA[ARENA_SZ];
  char* LA = ARENA;
  char* LB = ARENA + BM * 128;
  constexpr int WM = BM / 2, WN = BN / 2, FM = WM / 16, FN = WN / 16;
  const int tid = threadIdx.x, lane = tid & 63, wave = tid >> 6;
  const int wr = (wave >> 1) * WM, wc = (wave & 1) * WN;
  const int m0 = blockIdx.y * BM, n0 = blockIdx.x * BN;
  f32x4 acc[FM][FN] = {};
  for (int k0 = 0; k0 < K; k0 += 64) {
#pragma unroll
    for (int r = 0; r < BM / 32; ++r) {
      int o = r * 4096 + tid * 16;
      int row = o >> 7;
      int ce = (((o & 127) ^ ((row & 7) << 4)) >> 1);   // pre-swizzled src col
      gload16(A + (size_t)(m0 + row) * K + k0 + ce, LA + o);
    }
#pragma unroll
    for (int r = 0; r < BN / 32; ++r) {
      int o = r * 4096 + tid * 16;
      int row = o >> 7;
      int ce = (((o & 127) ^ ((row & 7) << 4)) >> 1);
      gload16(Bm + (size_t)(n0 + row) * K + k0 + ce, LB + o);
    }
    __syncthreads();
#pragma unroll
    for (int kk = 0; kk < 2; ++kk) {
      s8v af[FM], bf[FN];
#pragma unroll
      for (int m = 0; m < FM; ++m) {
        int row = wr + m * 16 + (lane & 15);
        int ad = ((row << 7) + kk * 64 + ((lane >> 4) << 4)) ^ ((row & 7) << 4);
        af[m] = *reinterpret_cast<const s8v*>(LA + ad);
      }
#pragma unroll
      for (int n = 0; n < FN; ++n) {
        int row = wc + n * 16 + (lane & 15);
        int ad = ((row << 7) + kk * 64 + ((lane >> 4) << 4)) ^ ((row & 7) << 4);
        bf[n] = *reinterpret_cast<const s8v*>(LB + ad);
      }
#pragma unroll
      for (int m = 0; m < FM; ++m)
#pragma unroll
        for (int n = 0; n < FN; ++n)
          acc[m][n] = mfma16(af[m], bf[n], acc[m][n]);
    }
    __syncthreads();
  }
  if constexpr (EPI == 0) {
    short* qkvb = (short*)Cout;
    if (n0 < 1536) {
#pragma unroll
      for (int m = 0; m < FM; ++m)
#pragma unroll
        for (int n = 0; n < FN; ++n)
#pragma unroll
          for (int r = 0; r < 4; ++r) {
            int row = m0 + wr + m * 16 + ((lane >> 4) << 2) + r;
            int col = n0 + wc + n * 16 + (lane & 15);
            float v = acc[m][n][r] + bias0[col];
            int w = col >> 9, h = (col >> 6) & 7, d = col & 63;
            int b = row >> 11, nn = row & 2047;
            qkvb[((((size_t)(w * 2 + b)) * 8 + h) * 2048 + nn) * 64 + d] = (short)f2b(v);
          }
    } else {
      // gate path: la into LDS transposed [col][row], stride 133 (2-way free)
      float* L = (float*)ARENA;
#pragma unroll
      for (int m = 0; m < FM; ++m)
#pragma unroll
        for (int n = 0; n < FN; ++n)
#pragma unroll
          for (int r = 0; r < 4; ++r) {
            int rloc = wr + m * 16 + ((lane >> 4) << 2) + r;
            int cloc = wc + n * 16 + (lane & 15);
            float xv = acc[m][n][r] + bias1[n0 + cloc - 1536];
            float a = 1.f / (1.f + expf(-xv));
            a = fminf(fmaxf(a, 1e-10f), 1.f);
            L[cloc * 133 + rloc] = logf(a);
          }
      __syncthreads();
      int c = tid & 127, ch = tid >> 7;
      int gc = n0 - 1536 + c;
      int h = gc >> 6, d = gc & 63;
      int b = m0 >> 11, nbase = (m0 & 2047) + ch * 64;
      int bh = b * 8 + h;
      const float* Lp = L + c * 133 + ch * 64;
      float* lp = lc + ((size_t)bh * 2048 + nbase) * 64 + d;
      float s = 0.f;
#pragma unroll 8
      for (int i = 0; i < 64; ++i) { s += Lp[i]; lp[(size_t)i * 64] = s; }
      csum[((size_t)bh * 32 + (nbase >> 6)) * 64 + d] = s;
    }
  } else {
    float* C = (float*)Cout;
#pragma unroll
    for (int m = 0; m < FM; ++m)
#pragma unroll
      for (int n = 0; n < FN; ++n)
#pragma unroll
        for (int r = 0; r < 4; ++r) {
          int row = m0 + wr + m * 16 + ((lane >> 4) << 2) + r;
          int col = n0 + wc + n * 16 + (lane & 15);
          C[(size_t)row * N + col] = acc[m][n][r] + bias0[col];
        }
  }
}

// ---------------- 3) scan2: gates -> q2,k2,vT + folded kstate (S per chunk) --
__global__ __launch_bounds__(256) void scan2_k(const short* __restrict__ qkvb,
                                               const float* __restrict__ lc,
                                               const float* __restrict__ csum,
                                               short* __restrict__ q2,
                                               short* __restrict__ k2,
                                               short* __restrict__ vT,
                                               short* __restrict__ Sbuf) {
  int chunk = blockIdx.x, bh = blockIdx.y;
  int tid = threadIdx.x, lane = tid & 63, wave = tid >> 6;
  int b = bh >> 3, h = bh & 7, d = lane;
  __shared__ short kL[64][72], vL[64][72];
  __shared__ __align__(16) char kT[8192], vTl[8192];
  float pre = 0.f;
  for (int c = 0; c < chunk; ++c) pre += csum[((size_t)bh * 32 + c) * 64 + d];
  const size_t WS = (size_t)2 * 8 * 2048 * 64;
  size_t base = (((size_t)b * 8 + h) * 2048 + chunk * 64) * 64 + d;
  size_t rowbase = ((size_t)bh * 2048 + chunk * 64) * 64 + d;
#pragma unroll 4
  for (int rr = 0; rr < 16; ++rr) {
    int r = wave * 16 + rr;
    float s = pre + lc[rowbase + r * 64];
    float g = expf(s);                       // a_cum
    float gi = 1.f / fmaxf(g, 1e-8f);        // a_cum_inv
    float qv = b2f((unsigned short)qkvb[base + r * 64]);
    float kv = b2f((unsigned short)qkvb[base + WS + r * 64]);
    short vb = qkvb[base + 2 * WS + r * 64];
    q2[rowbase + r * 64] = (short)f2b(qv * 0.125f * g);   // SCALE = 64^-0.5
    unsigned short kb = f2b(kv * gi);
    k2[rowbase + r * 64] = (short)kb;
    kL[r][d] = (short)kb;
    vL[r][d] = vb;
  }
  __syncthreads();
  // transpose to global vT and to LDS [d][j] tiles (XOR-swizzled) for kstate
  short* vTrow = vT + ((size_t)bh * 64 + d) * 2048 + chunk * 64;
#pragma unroll
  for (int gg = 0; gg < 2; ++gg) {
    int g8 = wave + gg * 4;
    s8v pk, pv;
#pragma unroll
    for (int j = 0; j < 8; ++j) { pk[j] = kL[g8 * 8 + j][d]; pv[j] = vL[g8 * 8 + j][d]; }
    *reinterpret_cast<s8v*>(vTrow + g8 * 8) = pv;
    int ad = ((d << 7) + g8 * 16) ^ ((d & 7) << 4);
    *reinterpret_cast<s8v*>(kT  + ad) = pk;
    *reinterpret_cast<s8v*>(vTl + ad) = pv;
  }
  __syncthreads();
  // kstate: wave w computes S rows [w*16,w*16+16): S[d][d'] = sum_j V[j][d] k2[j][d']
  f32x4 acc[4] = {};
#pragma unroll
  for (int kk = 0; kk < 2; ++kk) {
    int arow = wave * 16 + (lane & 15);
    int aad = ((arow << 7) + kk * 64 + ((lane >> 4) << 4)) ^ ((arow & 7) << 4);
    s8v av = *reinterpret_cast<const s8v*>(vTl + aad);
#pragma unroll
    for (int n = 0; n < 4; ++n) {
      int brow = n * 16 + (lane & 15);
      int bad = ((brow << 7) + kk * 64 + ((lane >> 4) << 4)) ^ ((brow & 7) << 4);
      acc[n] = mfma16(av, *reinterpret_cast<const s8v*>(kT + bad), acc[n]);
    }
  }
  short* Sp = Sbuf + ((size_t)bh * 32 + chunk) * 4096;
#pragma unroll
  for (int n = 0; n < 4; ++n)
#pragma unroll
    for (int r = 0; r < 4; ++r)
      Sp[(wave * 16 + ((lane >> 4) << 2) + r) * 64 + n * 16 + (lane & 15)] = (short)f2b(acc[n][r]);
}

// ---------------- 4) sprefix: exclusive prefix of states (fp32 acc, bf16 io) -
__global__ __launch_bounds__(256) void sprefix_k(const short* __restrict__ Sbuf,
                                                 short* __restrict__ Spre) {
  int bh = blockIdx.x >> 4;
  int e = ((blockIdx.x & 15) << 8) + threadIdx.x;
  size_t base = (size_t)bh * 32 * 4096 + e;
  float acc = 0.f;
  for (int c = 0; c < 32; ++c) {
    Spre[base + (size_t)c * 4096] = (short)f2b(acc);
    acc += b2f((unsigned short)Sbuf[base + (size_t)c * 4096]);
  }
}

// ---------------- 5) attnk: out = q2@Spre + tril(q2 k2^T)@v ------------------
__global__ __launch_bounds__(256) void attnk_k(const short* __restrict__ q2,
                                               const short* __restrict__ k2,
                                               const short* __restrict__ vT,
                                               const short* __restrict__ Spre,
                                               short* __restrict__ aout) {
  int chunk = blockIdx.x, bh = blockIdx.y;
  int tid = threadIdx.x, lane = tid & 63, wave = tid >> 6;
  __shared__ __align__(16) char LQ[8192], LK[8192], LV[8192], LS[8192], LP[8192];
#pragma unroll
  for (int rr = 0; rr < 2; ++rr) {
    int o = rr * 4096 + tid * 16;
    int row = o >> 7;
    int ce = (((o & 127) ^ ((row & 7) << 4)) >> 1);
    gload16(q2   + ((size_t)bh * 2048 + chunk * 64 + row) * 64 + ce, LQ + o);
    gload16(k2   + ((size_t)bh * 2048 + chunk * 64 + row) * 64 + ce, LK + o);
    gload16(vT   + ((size_t)bh * 64 + row) * 2048 + chunk * 64 + ce, LV + o);
    gload16(Spre + (((size_t)bh * 32 + chunk) * 64 + row) * 64 + ce, LS + o);
  }
  __syncthreads();
  f32x4 accS[4] = {}, accO[4] = {};
#pragma unroll
  for (int kk = 0; kk < 2; ++kk) {
    int arow = wave * 16 + (lane & 15);
    int aad = ((arow << 7) + kk * 64 + ((lane >> 4) << 4)) ^ ((arow & 7) << 4);
    s8v aq = *reinterpret_cast<const s8v*>(LQ + aad);
#pragma unroll
    for (int n = 0; n < 4; ++n) {
      int brow = n * 16 + (lane & 15);
      int bad = ((brow << 7) + kk * 64 + ((lane >> 4) << 4)) ^ ((brow & 7) << 4);
      accS[n] = mfma16(aq, *reinterpret_cast<const s8v*>(LK + bad), accS[n]);
      accO[n] = mfma16(aq, *reinterpret_cast<const s8v*>(LS + bad), accO[n]);
    }
  }
  // causal mask within chunk, write P (bf16, swizzled)
#pragma unroll
  for (int n = 0; n < 4; ++n)
#pragma unroll
    for (int r = 0; r < 4; ++r) {
      int i = wave * 16 + ((lane >> 4) << 2) + r;
      int j = n * 16 + (lane & 15);
      float v = (j <= i) ? accS[n][r] : 0.f;
      int ad = ((i << 7) + (j << 1)) ^ ((i & 7) << 4);
      *reinterpret_cast<short*>(LP + ad) = (short)f2b(v);
    }
  __syncthreads();
#pragma unroll
  for (int kk = 0; kk < 2; ++kk) {
    int arow = wave * 16 + (lane & 15);
    int aad = ((arow << 7) + kk * 64 + ((lane >> 4) << 4)) ^ ((arow & 7) << 4);
    s8v ap = *reinterpret_cast<const s8v*>(LP + aad);
#pragma unroll
    for (int n = 0; n < 4; ++n) {
      int brow = n * 16 + (lane & 15);
      int bad = ((brow << 7) + kk * 64 + ((lane >> 4) << 4)) ^ ((brow & 7) << 4);
      accO[n] = mfma16(ap, *reinterpret_cast<const s8v*>(LV + bad), accO[n]);
    }
  }
  int b = bh >> 3, h = bh & 7;
#pragma unroll
  for (int n = 0; n < 4; ++n)
#pragma unroll
    for (int r = 0; r < 4; ++r) {
      int i = wave * 16 + ((lane >> 4) << 2) + r;
      int col = h * 64 + n * 16 + (lane & 15);
      size_t row = (size_t)b * 2048 + chunk * 64 + i;
      aout[row * 512 + col] = (short)f2b(accO[n][r]);
    }
}

// ---------------------------------------------------------------------------
extern "C" void kernel_launch(void* const* d_in, const int* in_sizes, int n_in,
                              void* d_out, int out_size, void* d_ws, size_t ws_size,
                              hipStream_t stream) {
  const float* x     = (const float*)d_in[0];
  const float* gamma = (const float*)d_in[1];
  const float* w_qkv = (const float*)d_in[2];
  const float* b_qkv = (const float*)d_in[3];
  const float* w_a   = (const float*)d_in[4];
  const float* b_a   = (const float*)d_in[5];
  const float* w_out = (const float*)d_in[6];
  const float* b_out = (const float*)d_in[7];
  float* out = (float*)d_out;
  char* ws = (char*)d_ws;

  const size_t MB = 1u << 20;
  short* xnb  = (short*)(ws);                 // 4 MiB   [4096][512] bf16
  short* wT   = (short*)(ws + 4  * MB);       // 2 MiB   [2048][512] bf16
  short* woT  = (short*)(ws + 6  * MB);       // 0.5 MiB [512][512]  bf16
  short* qkvb = (short*)(ws + 7  * MB);       // 12 MiB  [3][2][8][2048][64] bf16
  float* lc   = (float*)(ws + 19 * MB);       // 16 MiB  [16][2048][64] f32
  float* csum = (float*)(ws + 35 * MB);       // 128 KiB [16][32][64] f32
  short* q2   = (short*)(ws + 36 * MB);       // 4 MiB   [16][2048][64] bf16
  short* k2   = (short*)(ws + 40 * MB);       // 4 MiB
  short* vT   = (short*)(ws + 44 * MB);       // 4 MiB   [16][64][2048]
  short* Sbuf = (short*)(ws + 48 * MB);       // 4 MiB   [16][32][64][64] bf16
  short* Spre = (short*)(ws + 52 * MB);       // 4 MiB
  short* aout = (short*)(ws + 56 * MB);       // 4 MiB   [4096][512] bf16

  prep_k<<<2304, 256, 0, stream>>>(x, gamma, xnb, w_qkv, w_a, w_out, wT, woT);

  gemm_bt<128, 128, 0><<<dim3(16, 32), 256, 0, stream>>>(
      xnb, wT, qkvb, b_qkv, b_a, lc, csum, 4096, 2048, 512);

  scan2_k<<<dim3(32, 16), 256, 0, stream>>>(qkvb, lc, csum, q2, k2, vT, Sbuf);

  sprefix_k<<<256, 256, 0, stream>>>(Sbuf, Spre);
  attnk_k<<<dim3(32, 16), 256, 0, stream>>>(q2, k2, vT, Spre, aout);

  gemm_bt<64, 64, 1><<<dim3(8, 64), 256, 0, stream>>>(
      aout, woT, out, b_out, b_out, nullptr, nullptr, 4096, 512, 512);
}